// Round 7
// baseline (220.405 us; speedup 1.0000x reference)
//
#include <hip/hip_runtime.h>
#include <math.h>

#define T_TOK 16384   // 4*4096 tokens
#define NEXP  64

// Workspace layout (floats):
//   ws[0..63]   : expert load sums
//   ws[64]      : sum of z^2
//   ws[66]      : block-done counter (int)
//   ws[67]      : known-zero word (opacity source for vector-w codegen)
//   ws[128 ..]  : w_t transposed gate weights [1024][64]
//
// d_out layout (floats, out_size = 65537):
//   [0, 32768)      top-2 renormalized scores [token][2]
//   [32768, 65536)  top-2 expert indices as floats [token][2]
//   [65536]         total_loss

// ---------------------------------------------------------------------------
// prep: tiled transpose gate_w [64][1024] -> w_t [1024][64]; zero accumulators
// (ws[0..127], incl. done-counter ws[66] and the zero word ws[67]).
// ---------------------------------------------------------------------------
__global__ void moe_prep(const float* __restrict__ gw, float* __restrict__ ws) {
    __shared__ float tile[64][65];
    const int b = blockIdx.x;
    const int tid = threadIdx.x;         // 256
    if (b == 0 && tid < 128) ws[tid] = 0.f;
#pragma unroll
    for (int it = 0; it < 16; ++it) {
        int idx = it * 256 + tid;
        int e = idx >> 6, kk = idx & 63;
        tile[e][kk] = gw[e * 1024 + b * 64 + kk];
    }
    __syncthreads();
#pragma unroll
    for (int it = 0; it < 16; ++it) {
        int idx = it * 256 + tid;
        int kk = idx >> 6, e = idx & 63;
        ws[128 + (b * 64 + kk) * 64 + e] = tile[e][kk];
    }
}

// ---------------------------------------------------------------------------
// main: round-4 structure, but the w stream is VECTOR loads (global_load_
// dwordx4, deeply pipelined via vmcnt + 256-VGPR budget) instead of s_load
// (only ~4-5 in flight on the SGPR file -> the 55 us stall). Divergence is
// forced by a volatile load of a known-zero ws word (a loaded value is
// divergent by definition -> address in VGPRs -> VMEM codegen). All lanes
// load the same address -> single broadcast L1 transaction; each wave reads
// a disjoint 32 KB slice of w per block (L2-resident).
// ---------------------------------------------------------------------------
__launch_bounds__(512, 2)
__global__ void moe_main(const float* __restrict__ x,
                         const float* __restrict__ wt,     // [1024][64]
                         float* __restrict__ acc_ws,
                         float* __restrict__ out) {
    __shared__ float xbuf[2][4096];      // [K-half][row*64 + swz chunk], 32 KiB
    __shared__ float sc[64][65];         // logits -> exp scores
    __shared__ float row_inv[64];
    __shared__ float colpart[8][64];
    __shared__ int   is_last;

    const int tid  = threadIdx.x;
    const int lane = tid & 63;
    const int wv   = tid >> 6;
    const int g = __builtin_amdgcn_readfirstlane(wv & 3);   // expert group
    const int h = __builtin_amdgcn_readfirstlane(wv >> 2);  // K half
    const int tok0 = blockIdx.x << 6;

    // Opaque zero: volatile load of ws[67] (zeroed by prep, stream-ordered).
    // Loaded values are divergent -> forces VMEM codegen for the w stream.
    const int vzero = *(const volatile int*)(acc_ws + 67);

    // staging: 2048 chunks/step, 4 per thread at rows rr0+{0,4,8,12} of
    // K-tile (wv>>2); one base pointer + named offsets.
    const int tile = wv >> 2;
    const int rr0  = ((wv & 3) << 4) + (lane >> 4);
    const int cg   = lane & 15;
    const float* gbase = x + (((size_t)(tok0 + rr0)) << 10) + (tile << 9) + (cg << 2);
    const int lo0 = (tile << 12) + ((rr0 +  0) << 6) + ((cg ^ ((rr0 +  0) & 15)) << 2);
    const int lo1 = (tile << 12) + ((rr0 +  4) << 6) + ((cg ^ ((rr0 +  4) & 15)) << 2);
    const int lo2 = (tile << 12) + ((rr0 +  8) << 6) + ((cg ^ ((rr0 +  8) & 15)) << 2);
    const int lo3 = (tile << 12) + ((rr0 + 12) << 6) + ((cg ^ ((rr0 + 12) & 15)) << 2);
    float* xb = &xbuf[0][0];

    float acc[16];
#pragma unroll
    for (int e = 0; e < 16; ++e) acc[e] = 0.f;

    // prologue prefetch of step 0
    float4 p0 = *(const float4*)(gbase);
    float4 p1 = *(const float4*)(gbase + 4096);
    float4 p2 = *(const float4*)(gbase + 8192);
    float4 p3 = *(const float4*)(gbase + 12288);

    const int swz = cg;
    const float* xrow = &xbuf[h][lane << 6];

#pragma unroll 1
    for (int s = 0; s < 8; ++s) {
        __syncthreads();                                  // xbuf free
        *(float4*)(xb + lo0) = p0;
        *(float4*)(xb + lo1) = p1;
        *(float4*)(xb + lo2) = p2;
        *(float4*)(xb + lo3) = p3;
        __syncthreads();                                  // xbuf ready
        if (s < 7) {                                      // prefetch next step
            const float* gs = gbase + ((s + 1) << 6);
            p0 = *(const float4*)(gs);
            p1 = *(const float4*)(gs + 4096);
            p2 = *(const float4*)(gs + 8192);
            p3 = *(const float4*)(gs + 12288);
        }
        // k = h*512 + s*64 + c*4 + j ; w via VECTOR loads (vmcnt pipeline)
        const float* wv4 = wt + (((h << 9) + (s << 6)) << 6) + (g << 4) + vzero;
#pragma unroll
        for (int c = 0; c < 16; ++c) {
            float4 xv = *(const float4*)(xrow + ((c ^ swz) << 2));
            float xa[4] = {xv.x, xv.y, xv.z, xv.w};
#pragma unroll
            for (int j = 0; j < 4; ++j) {
                const float* wkj = wv4 + (((c << 2) + j) << 6);
                float4 w0 = *(const float4*)(wkj);
                float4 w1 = *(const float4*)(wkj + 4);
                float4 w2 = *(const float4*)(wkj + 8);
                float4 w3 = *(const float4*)(wkj + 12);
                float xj = xa[j];
                acc[ 0] = fmaf(xj, w0.x, acc[ 0]);
                acc[ 1] = fmaf(xj, w0.y, acc[ 1]);
                acc[ 2] = fmaf(xj, w0.z, acc[ 2]);
                acc[ 3] = fmaf(xj, w0.w, acc[ 3]);
                acc[ 4] = fmaf(xj, w1.x, acc[ 4]);
                acc[ 5] = fmaf(xj, w1.y, acc[ 5]);
                acc[ 6] = fmaf(xj, w1.z, acc[ 6]);
                acc[ 7] = fmaf(xj, w1.w, acc[ 7]);
                acc[ 8] = fmaf(xj, w2.x, acc[ 8]);
                acc[ 9] = fmaf(xj, w2.y, acc[ 9]);
                acc[10] = fmaf(xj, w2.z, acc[10]);
                acc[11] = fmaf(xj, w2.w, acc[11]);
                acc[12] = fmaf(xj, w3.x, acc[12]);
                acc[13] = fmaf(xj, w3.y, acc[13]);
                acc[14] = fmaf(xj, w3.z, acc[14]);
                acc[15] = fmaf(xj, w3.w, acc[15]);
            }
        }
    }

    // ---- combine K halves into sc[token][expert]
    if (h == 0) {
#pragma unroll
        for (int e = 0; e < 16; ++e) sc[lane][(g << 4) + e] = acc[e];
    }
    __syncthreads();
    if (h == 1) {
#pragma unroll
        for (int e = 0; e < 16; ++e) sc[lane][(g << 4) + e] += acc[e];
    }
    __syncthreads();

    // ---- per-token epilogue (serial, 0 bank conflicts, proven absmax 0)
    if (tid < 64) {
        const int r = tid;
        float v1 = -1e30f, v2 = -1e30f;
        int i1 = 0, i2 = 0;
        for (int j = 0; j < 64; ++j) {
            float l = sc[r][j];
            if (l > v1)      { v2 = v1; i2 = i1; v1 = l; i1 = j; }
            else if (l > v2) { v2 = l; i2 = j; }
        }
        float m = v1;
        float ssum = 0.f;
        for (int j = 0; j < 64; ++j) {
            float ev = expf(sc[r][j] - m);
            ssum += ev;
            sc[r][j] = ev;
        }
        float inv = 1.f / ssum;
        row_inv[r] = inv;
        float z = m + logf(ssum);
        float zsq = z * z;
#pragma unroll
        for (int off = 32; off > 0; off >>= 1) zsq += __shfl_down(zsq, off);
        if (lane == 0) atomicAdd(acc_ws + 64, zsq);

        float p1s = inv;                        // exp(v1-m) == 1
        float p2s = expf(v2 - m) * inv;
        float bb  = expf(p2s - p1s);
        float s1 = 1.f / (1.f + bb);
        float s2 = bb * s1;
        int t = tok0 + r;
        out[2 * t]     = s1;
        out[2 * t + 1] = s2;
        out[2 * T_TOK + 2 * t]     = (float)i1;
        out[2 * T_TOK + 2 * t + 1] = (float)i2;
    }
    __syncthreads();

    // ---- expert load column sums
    {
        int e  = tid & 63;
        int rg = tid >> 6;
        float sum = 0.f;
#pragma unroll
        for (int r2 = 0; r2 < 8; ++r2) {
            int row = (rg << 3) + r2;
            sum += sc[row][e] * row_inv[row];
        }
        colpart[rg][e] = sum;
    }
    __syncthreads();
    if (tid < 64) {
        float tot = 0.f;
#pragma unroll
        for (int rg = 0; rg < 8; ++rg) tot += colpart[rg][tid];
        atomicAdd(acc_ws + tid, tot);           // device-scope
    }

    // ---- last-block finalize
    __syncthreads();
    if (tid == 0) {
        __threadfence();
        int old = __hip_atomic_fetch_add((int*)(acc_ws + 66), 1,
                                         __ATOMIC_ACQ_REL, __HIP_MEMORY_SCOPE_AGENT);
        is_last = (old == 255) ? 1 : 0;
    }
    __syncthreads();
    if (is_last && tid < 64) {
        __threadfence();
        float load = __hip_atomic_load(acc_ws + tid, __ATOMIC_RELAXED,
                                       __HIP_MEMORY_SCOPE_AGENT) * (1.f / 16384.f);
        float d = load - (1.f / 64.f);
        float v = d * d;
#pragma unroll
        for (int off = 32; off > 0; off >>= 1) v += __shfl_down(v, off);
        if (tid == 0) {
            float zsum = __hip_atomic_load(acc_ws + 64, __ATOMIC_RELAXED,
                                           __HIP_MEMORY_SCOPE_AGENT);
            float lb = 0.01f * 64.f * v;
            float zl = 1e-4f * zsum * (1.f / 16384.f);
            out[4 * T_TOK] = lb + zl;
        }
    }
}

extern "C" void kernel_launch(void* const* d_in, const int* in_sizes, int n_in,
                              void* d_out, int out_size, void* d_ws, size_t ws_size,
                              hipStream_t stream) {
    const float* x  = (const float*)d_in[0];   // [4,4096,1024] fp32
    const float* gw = (const float*)d_in[1];   // [64,1024] fp32
    float* out = (float*)d_out;                // 65537 fp32
    float* ws  = (float*)d_ws;

    moe_prep<<<16, 256, 0, stream>>>(gw, ws);
    moe_main<<<256, 512, 0, stream>>>(x, ws + 128, ws, out);
}

// Round 8
// 134.781 us; speedup vs baseline: 1.6353x; 1.6353x over previous
//
#include <hip/hip_runtime.h>
#include <math.h>

#define T_TOK 16384   // 4*4096 tokens
#define NEXP  64

// Workspace layout (floats):
//   ws[0..63]   : expert load sums
//   ws[64]      : sum of z^2
//   ws[66]      : block-done counter (int)
//   ws[128 ..]  : w_t transposed gate weights [1024][64]
//
// d_out layout (floats, out_size = 65537):
//   [0, 32768)      top-2 renormalized scores [token][2]
//   [32768, 65536)  top-2 expert indices as floats [token][2]
//   [65536]         total_loss

// ---------------------------------------------------------------------------
// prep: tiled transpose gate_w [64][1024] -> w_t [1024][64]; zero accumulators
// ---------------------------------------------------------------------------
__global__ void moe_prep(const float* __restrict__ gw, float* __restrict__ ws) {
    __shared__ float tile[64][65];
    const int b = blockIdx.x;
    const int tid = threadIdx.x;         // 256
    if (b == 0 && tid < 128) ws[tid] = 0.f;
#pragma unroll
    for (int it = 0; it < 16; ++it) {
        int idx = it * 256 + tid;
        int e = idx >> 6, kk = idx & 63;
        tile[e][kk] = gw[e * 1024 + b * 64 + kk];
    }
    __syncthreads();
#pragma unroll
    for (int it = 0; it < 16; ++it) {
        int idx = it * 256 + tid;
        int kk = idx >> 6, e = idx & 63;
        ws[128 + (b * 64 + kk) * 64 + e] = tile[e][kk];
    }
}

// ---------------------------------------------------------------------------
// main: round-4 kernel (proven pure-FMA codegen, s_load w) with occupancy
// doubled: 1024 threads = 16 waves = g(4) x h(4). Wave (g,h): expert group
// g, K-half h>>1, chunk-quarter h&1 (32 k of each staged 64-k step).
// Grid 256 -> 16 waves/CU = 4 waves/SIMD: s_load stall (~530 cyc/c-iter)
// now covered by 4x128 cyc of other-wave FMA issue. Staging layout and
// inner-loop shape byte-identical to round 4 (s_load w, 0 bank conflicts).
// ---------------------------------------------------------------------------
__launch_bounds__(1024, 4)
__global__ void moe_main(const float* __restrict__ x,
                         const float* __restrict__ wt,     // [1024][64]
                         float* __restrict__ acc_ws,
                         float* __restrict__ out) {
    __shared__ float xbuf[2][4096];      // [K-half][row*64 + swz chunk], 32 KiB
    __shared__ float sc[64][65];         // logits -> exp scores
    __shared__ float row_inv[64];
    __shared__ float colpart[16][64];
    __shared__ int   is_last;

    const int tid  = threadIdx.x;
    const int lane = tid & 63;
    const int wv   = tid >> 6;                              // 0..15
    const int g     = __builtin_amdgcn_readfirstlane(wv & 3);    // expert group
    const int h     = __builtin_amdgcn_readfirstlane(wv >> 2);   // 0..3
    const int khalf = __builtin_amdgcn_readfirstlane(h >> 1);    // K half
    const int cq    = __builtin_amdgcn_readfirstlane(h & 1);     // chunk quarter
    const int tok0 = blockIdx.x << 6;

    // staging: 2048 chunks/step, 2 per thread (same row/cg in both K-half
    // slabs). Global pair differs by constant +512 floats; LDS by +4096.
    const int rr = tid >> 4;             // 0..63
    const int cg = tid & 15;
    const float* gbase = x + (((size_t)(tok0 + rr)) << 10) + (cg << 2);
    const int lo = (rr << 6) + ((cg ^ (rr & 15)) << 2);
    float* xb = &xbuf[0][0];

    float acc[16];
#pragma unroll
    for (int e = 0; e < 16; ++e) acc[e] = 0.f;

    // prologue prefetch of step 0 (named regs)
    float4 p0 = *(const float4*)(gbase);
    float4 p1 = *(const float4*)(gbase + 512);

    const int swz = lane & 15;
    const float* xrow = &xbuf[khalf][lane << 6];

#pragma unroll 1
    for (int s = 0; s < 8; ++s) {
        __syncthreads();                                  // xbuf free
        *(float4*)(xb + lo)        = p0;
        *(float4*)(xb + lo + 4096) = p1;
        __syncthreads();                                  // xbuf ready
        if (s < 7) {                                      // prefetch next step
            const float* gs = gbase + ((s + 1) << 6);
            p0 = *(const float4*)(gs);
            p1 = *(const float4*)(gs + 512);
        }
        // k = khalf*512 + s*64 + cc*4 + j ; this wave: cc in [cq*8, cq*8+8)
        const float* wrow = wt + (((khalf << 9) + (s << 6)) << 6) + (g << 4);
#pragma unroll
        for (int c = 0; c < 8; ++c) {
            int cc = (cq << 3) + c;
            float4 xv = *(const float4*)(xrow + ((cc ^ swz) << 2));
            float xa[4] = {xv.x, xv.y, xv.z, xv.w};
#pragma unroll
            for (int j = 0; j < 4; ++j) {
                const float* wkj = wrow + (((cc << 2) + j) << 6);  // uniform -> s_load
                float xj = xa[j];
#pragma unroll
                for (int e = 0; e < 16; ++e)
                    acc[e] = fmaf(xj, wkj[e], acc[e]);
            }
        }
    }

    // ---- combine 4 partials into sc[token][expert] (barrier chain)
    if (h == 0) {
#pragma unroll
        for (int e = 0; e < 16; ++e) sc[lane][(g << 4) + e] = acc[e];
    }
    __syncthreads();
    if (h == 1) {
#pragma unroll
        for (int e = 0; e < 16; ++e) sc[lane][(g << 4) + e] += acc[e];
    }
    __syncthreads();
    if (h == 2) {
#pragma unroll
        for (int e = 0; e < 16; ++e) sc[lane][(g << 4) + e] += acc[e];
    }
    __syncthreads();
    if (h == 3) {
#pragma unroll
        for (int e = 0; e < 16; ++e) sc[lane][(g << 4) + e] += acc[e];
    }
    __syncthreads();

    // ---- per-token epilogue (serial, 0 bank conflicts, proven absmax 0)
    if (tid < 64) {
        const int r = tid;
        float v1 = -1e30f, v2 = -1e30f;
        int i1 = 0, i2 = 0;
        for (int j = 0; j < 64; ++j) {
            float l = sc[r][j];
            if (l > v1)      { v2 = v1; i2 = i1; v1 = l; i1 = j; }
            else if (l > v2) { v2 = l; i2 = j; }
        }
        float m = v1;
        float ssum = 0.f;
        for (int j = 0; j < 64; ++j) {
            float ev = expf(sc[r][j] - m);
            ssum += ev;
            sc[r][j] = ev;
        }
        float inv = 1.f / ssum;
        row_inv[r] = inv;
        float z = m + logf(ssum);
        float zsq = z * z;
#pragma unroll
        for (int off = 32; off > 0; off >>= 1) zsq += __shfl_down(zsq, off);
        if (lane == 0) atomicAdd(acc_ws + 64, zsq);

        float p1s = inv;                        // exp(v1-m) == 1
        float p2s = expf(v2 - m) * inv;
        float bb  = expf(p2s - p1s);
        float s1 = 1.f / (1.f + bb);
        float s2 = bb * s1;
        int t = tok0 + r;
        out[2 * t]     = s1;
        out[2 * t + 1] = s2;
        out[2 * T_TOK + 2 * t]     = (float)i1;
        out[2 * T_TOK + 2 * t + 1] = (float)i2;
    }
    __syncthreads();

    // ---- expert load column sums (1024 threads: 16 row-groups of 4 rows)
    {
        int e  = tid & 63;
        int rg = tid >> 6;                      // 0..15
        float sum = 0.f;
#pragma unroll
        for (int r2 = 0; r2 < 4; ++r2) {
            int row = (rg << 2) + r2;
            sum += sc[row][e] * row_inv[row];
        }
        colpart[rg][e] = sum;
    }
    __syncthreads();
    if (tid < 64) {
        float tot = 0.f;
#pragma unroll
        for (int rg = 0; rg < 16; ++rg) tot += colpart[rg][tid];
        atomicAdd(acc_ws + tid, tot);           // device-scope
    }

    // ---- last-block finalize
    __syncthreads();
    if (tid == 0) {
        __threadfence();
        int old = __hip_atomic_fetch_add((int*)(acc_ws + 66), 1,
                                         __ATOMIC_ACQ_REL, __HIP_MEMORY_SCOPE_AGENT);
        is_last = (old == 255) ? 1 : 0;
    }
    __syncthreads();
    if (is_last && tid < 64) {
        __threadfence();
        float load = __hip_atomic_load(acc_ws + tid, __ATOMIC_RELAXED,
                                       __HIP_MEMORY_SCOPE_AGENT) * (1.f / 16384.f);
        float d = load - (1.f / 64.f);
        float v = d * d;
#pragma unroll
        for (int off = 32; off > 0; off >>= 1) v += __shfl_down(v, off);
        if (tid == 0) {
            float zsum = __hip_atomic_load(acc_ws + 64, __ATOMIC_RELAXED,
                                           __HIP_MEMORY_SCOPE_AGENT);
            float lb = 0.01f * 64.f * v;
            float zl = 1e-4f * zsum * (1.f / 16384.f);
            out[4 * T_TOK] = lb + zl;
        }
    }
}

extern "C" void kernel_launch(void* const* d_in, const int* in_sizes, int n_in,
                              void* d_out, int out_size, void* d_ws, size_t ws_size,
                              hipStream_t stream) {
    const float* x  = (const float*)d_in[0];   // [4,4096,1024] fp32
    const float* gw = (const float*)d_in[1];   // [64,1024] fp32
    float* out = (float*)d_out;                // 65537 fp32
    float* ws  = (float*)d_ws;

    moe_prep<<<16, 256, 0, stream>>>(gw, ws);
    moe_main<<<256, 1024, 0, stream>>>(x, ws + 128, ws, out);
}

// Round 9
// 130.633 us; speedup vs baseline: 1.6872x; 1.0317x over previous
//
#include <hip/hip_runtime.h>
#include <math.h>

#define T_TOK 16384   // 4*4096 tokens
#define NEXP  64

// Workspace layout (floats):
//   ws[0..63]   : expert load sums
//   ws[64]      : sum of z^2
//   ws[66]      : block-done counter (int)
//   ws[128 ..]  : w_t transposed gate weights [1024][64]
//
// d_out layout (floats, out_size = 65537):
//   [0, 32768)      top-2 renormalized scores [token][2]
//   [32768, 65536)  top-2 expert indices as floats [token][2]
//   [65536]         total_loss

// ---------------------------------------------------------------------------
// prep: tiled transpose gate_w [64][1024] -> w_t [1024][64]; zero accumulators
// ---------------------------------------------------------------------------
__global__ void moe_prep(const float* __restrict__ gw, float* __restrict__ ws) {
    __shared__ float tile[64][65];
    const int b = blockIdx.x;
    const int tid = threadIdx.x;         // 256
    if (b == 0 && tid < 128) ws[tid] = 0.f;
#pragma unroll
    for (int it = 0; it < 16; ++it) {
        int idx = it * 256 + tid;
        int e = idx >> 6, kk = idx & 63;
        tile[e][kk] = gw[e * 1024 + b * 64 + kk];
    }
    __syncthreads();
#pragma unroll
    for (int it = 0; it < 16; ++it) {
        int idx = it * 256 + tid;
        int kk = idx >> 6, e = idx & 63;
        ws[128 + (b * 64 + kk) * 64 + e] = tile[e][kk];
    }
}

// ---------------------------------------------------------------------------
// main: register-tiled fp32 GEMM. Block = 64 t x 64 e, 1024 threads = 16
// waves = 4 (t,e)-tiles (32x32) x 4 k-quarters. Each lane owns a 4t x 4e
// tile: per 4-k group, 4 x-frags + 4 w-frags (8 ds_read_b128, both per-lane
// register operands) feed 64 FMAs -- NO broadcast operand stream (the
// scalar-pipe 4B-per-FMA w stream was the ~45 us stall in rounds 4-8).
// Step = 16 k per quarter (64 k total), two barriers per step (proven shape).
// ---------------------------------------------------------------------------
__launch_bounds__(1024, 4)
__global__ void moe_main(const float* __restrict__ x,
                         const float* __restrict__ wt,     // [1024][64]
                         float* __restrict__ acc_ws,
                         float* __restrict__ out) {
    __shared__ float xbuf[4096];         // x slab: [t 64][chunk 16 ^ swz][4]
    __shared__ float wbuf[4096];         // w slab: [row 64][e 64] (straight copy)
    __shared__ float sc[64 * 68];        // logits, stride 68 (16B-aligned rows)
    __shared__ float row_inv[64];
    __shared__ float colpart[16][64];
    __shared__ int   is_last;

    const int tid  = threadIdx.x;
    const int lane = tid & 63;
    const int wv   = tid >> 6;                                   // 0..15
    const int kq   = __builtin_amdgcn_readfirstlane(wv & 3);     // k quarter
    const int tile = __builtin_amdgcn_readfirstlane(wv >> 2);    // (t,e) tile
    const int tt = tile >> 1, te = tile & 1;
    const int ta = lane >> 3;            // token-quad within tile (0..7)
    const int eb = lane & 7;             // expert-quad within tile (0..7)
    const int tok0 = blockIdx.x << 6;

    // ---- staging plan (1024 threads, 1 float4 each for x and w per step)
    // x: thread (rr = t, cg): global k = (cg>>2)*256 + s*16 + (cg&3)*4
    const int rr = tid >> 4;             // 0..63
    const int cg = tid & 15;
    const float* gx = x + (((size_t)(tok0 + rr)) << 10) + ((cg >> 2) << 8) + ((cg & 3) << 2);
    const int xlo = (rr << 6) + ((cg ^ (rr & 15)) << 2);
    // w: row rr covers global k = (rr>>4)*256 + s*16 + (rr&15); straight copy
    const float* gw = wt + ((((rr >> 4) << 8) + (rr & 15)) << 6) + (cg << 2);
    const int wlo = (rr << 6) + (cg << 2);

    float acc[16];
#pragma unroll
    for (int e = 0; e < 16; ++e) acc[e] = 0.f;

    // ---- per-lane read bases
    const int t0 = (tt << 5) + (ta << 2);           // token base within block
    const float* xrow0 = xbuf + ((t0 + 0) << 6);
    const float* xrow1 = xbuf + ((t0 + 1) << 6);
    const float* xrow2 = xbuf + ((t0 + 2) << 6);
    const float* xrow3 = xbuf + ((t0 + 3) << 6);
    const int c0 = (t0 + 0) & 15, c1 = (t0 + 1) & 15;
    const int c2 = (t0 + 2) & 15, c3 = (t0 + 3) & 15;
    const int ebase = (te << 5) + (eb << 2);        // expert base within block
    const float* wp = wbuf + (kq << 10) + ebase;    // + (4*g4+u)*64 (imm)
    const int cwb = kq << 2;                        // x chunk base: cw = cwb+g4

    // prologue prefetch of step 0 (two named float4 regs)
    float4 px = *(const float4*)gx;
    float4 pw = *(const float4*)gw;

#pragma unroll 1
    for (int s = 0; s < 16; ++s) {
        __syncthreads();                            // bufs free
        *(float4*)(xbuf + xlo) = px;
        *(float4*)(wbuf + wlo) = pw;
        __syncthreads();                            // bufs ready
        if (s < 15) {                               // prefetch next step
            px = *(const float4*)(gx + ((s + 1) << 4));
            pw = *(const float4*)(gw + ((s + 1) << 10));
        }
#pragma unroll
        for (int g4 = 0; g4 < 4; ++g4) {
            const int cw = cwb + g4;
            float4 xf0 = *(const float4*)(xrow0 + ((cw ^ c0) << 2));
            float4 xf1 = *(const float4*)(xrow1 + ((cw ^ c1) << 2));
            float4 xf2 = *(const float4*)(xrow2 + ((cw ^ c2) << 2));
            float4 xf3 = *(const float4*)(xrow3 + ((cw ^ c3) << 2));
            const float* wq = wp + (g4 << 8);
            float4 wf0 = *(const float4*)(wq);
            float4 wf1 = *(const float4*)(wq + 64);
            float4 wf2 = *(const float4*)(wq + 128);
            float4 wf3 = *(const float4*)(wq + 192);
            float xa[16] = {xf0.x, xf0.y, xf0.z, xf0.w,
                            xf1.x, xf1.y, xf1.z, xf1.w,
                            xf2.x, xf2.y, xf2.z, xf2.w,
                            xf3.x, xf3.y, xf3.z, xf3.w};
            float wa[16] = {wf0.x, wf0.y, wf0.z, wf0.w,
                            wf1.x, wf1.y, wf1.z, wf1.w,
                            wf2.x, wf2.y, wf2.z, wf2.w,
                            wf3.x, wf3.y, wf3.z, wf3.w};
#pragma unroll
            for (int i = 0; i < 4; ++i)
#pragma unroll
                for (int u = 0; u < 4; ++u) {
                    float xv = xa[(i << 2) + u];
#pragma unroll
                    for (int j = 0; j < 4; ++j)
                        acc[(i << 2) + j] = fmaf(xv, wa[(u << 2) + j], acc[(i << 2) + j]);
                }
        }
    }

    // ---- combine 4 k-quarter partials into sc (barrier chain over kq)
    if (kq == 0) {
#pragma unroll
        for (int i = 0; i < 4; ++i) {
            float4 v = make_float4(acc[(i << 2)], acc[(i << 2) + 1],
                                   acc[(i << 2) + 2], acc[(i << 2) + 3]);
            *(float4*)(sc + (t0 + i) * 68 + ebase) = v;
        }
    }
    __syncthreads();
    if (kq == 1) {
#pragma unroll
        for (int i = 0; i < 4; ++i) {
            float4 o = *(float4*)(sc + (t0 + i) * 68 + ebase);
            o.x += acc[(i << 2)];     o.y += acc[(i << 2) + 1];
            o.z += acc[(i << 2) + 2]; o.w += acc[(i << 2) + 3];
            *(float4*)(sc + (t0 + i) * 68 + ebase) = o;
        }
    }
    __syncthreads();
    if (kq == 2) {
#pragma unroll
        for (int i = 0; i < 4; ++i) {
            float4 o = *(float4*)(sc + (t0 + i) * 68 + ebase);
            o.x += acc[(i << 2)];     o.y += acc[(i << 2) + 1];
            o.z += acc[(i << 2) + 2]; o.w += acc[(i << 2) + 3];
            *(float4*)(sc + (t0 + i) * 68 + ebase) = o;
        }
    }
    __syncthreads();
    if (kq == 3) {
#pragma unroll
        for (int i = 0; i < 4; ++i) {
            float4 o = *(float4*)(sc + (t0 + i) * 68 + ebase);
            o.x += acc[(i << 2)];     o.y += acc[(i << 2) + 1];
            o.z += acc[(i << 2) + 2]; o.w += acc[(i << 2) + 3];
            *(float4*)(sc + (t0 + i) * 68 + ebase) = o;
        }
    }
    __syncthreads();

    // ---- per-token epilogue (serial, proven absmax 0)
    if (tid < 64) {
        const int r = tid;
        const float* srow = sc + r * 68;
        float v1 = -1e30f, v2 = -1e30f;
        int i1 = 0, i2 = 0;
        for (int j = 0; j < 64; ++j) {
            float l = srow[j];
            if (l > v1)      { v2 = v1; i2 = i1; v1 = l; i1 = j; }
            else if (l > v2) { v2 = l; i2 = j; }
        }
        float m = v1;
        float ssum = 0.f;
        for (int j = 0; j < 64; ++j) {
            float ev = expf(srow[j] - m);
            ssum += ev;
            sc[r * 68 + j] = ev;
        }
        float inv = 1.f / ssum;
        row_inv[r] = inv;
        float z = m + logf(ssum);
        float zsq = z * z;
#pragma unroll
        for (int off = 32; off > 0; off >>= 1) zsq += __shfl_down(zsq, off);
        if (lane == 0) atomicAdd(acc_ws + 64, zsq);

        float p1s = inv;                        // exp(v1-m) == 1
        float p2s = expf(v2 - m) * inv;
        float bb  = expf(p2s - p1s);
        float s1 = 1.f / (1.f + bb);
        float s2 = bb * s1;
        int t = tok0 + r;
        out[2 * t]     = s1;
        out[2 * t + 1] = s2;
        out[2 * T_TOK + 2 * t]     = (float)i1;
        out[2 * T_TOK + 2 * t + 1] = (float)i2;
    }
    __syncthreads();

    // ---- expert load column sums (16 row-groups of 4 rows)
    {
        int e  = tid & 63;
        int rg = tid >> 6;                      // 0..15
        float sum = 0.f;
#pragma unroll
        for (int r2 = 0; r2 < 4; ++r2) {
            int row = (rg << 2) + r2;
            sum += sc[row * 68 + e] * row_inv[row];
        }
        colpart[rg][e] = sum;
    }
    __syncthreads();
    if (tid < 64) {
        float tot = 0.f;
#pragma unroll
        for (int rg = 0; rg < 16; ++rg) tot += colpart[rg][tid];
        atomicAdd(acc_ws + tid, tot);           // device-scope
    }

    // ---- last-block finalize
    __syncthreads();
    if (tid == 0) {
        __threadfence();
        int old = __hip_atomic_fetch_add((int*)(acc_ws + 66), 1,
                                         __ATOMIC_ACQ_REL, __HIP_MEMORY_SCOPE_AGENT);
        is_last = (old == 255) ? 1 : 0;
    }
    __syncthreads();
    if (is_last && tid < 64) {
        __threadfence();
        float load = __hip_atomic_load(acc_ws + tid, __ATOMIC_RELAXED,
                                       __HIP_MEMORY_SCOPE_AGENT) * (1.f / 16384.f);
        float d = load - (1.f / 64.f);
        float v = d * d;
#pragma unroll
        for (int off = 32; off > 0; off >>= 1) v += __shfl_down(v, off);
        if (tid == 0) {
            float zsum = __hip_atomic_load(acc_ws + 64, __ATOMIC_RELAXED,
                                           __HIP_MEMORY_SCOPE_AGENT);
            float lb = 0.01f * 64.f * v;
            float zl = 1e-4f * zsum * (1.f / 16384.f);
            out[4 * T_TOK] = lb + zl;
        }
    }
}

extern "C" void kernel_launch(void* const* d_in, const int* in_sizes, int n_in,
                              void* d_out, int out_size, void* d_ws, size_t ws_size,
                              hipStream_t stream) {
    const float* x  = (const float*)d_in[0];   // [4,4096,1024] fp32
    const float* gw = (const float*)d_in[1];   // [64,1024] fp32
    float* out = (float*)d_out;                // 65537 fp32
    float* ws  = (float*)d_ws;

    moe_prep<<<16, 256, 0, stream>>>(gw, ws);
    moe_main<<<256, 1024, 0, stream>>>(x, ws + 128, ws, out);
}